// Round 3
// baseline (132.540 us; speedup 1.0000x reference)
//
#include <hip/hip_runtime.h>

// AMPS chain kernel v9 — atomic-free final reduction. gfx950.
//
// amps_seg (unchanged, at HBM floor ~10.5us for the 67MB tri read):
// each 64-lane wave processes TWO (chain,segment) tasks (32 lanes each).
// Lane = (task t, batch b, row i) holds row i of the running 4x4 product C
// in 4 VGPRs. Step update = 16 register FMAs (4 independent chains of 4).
// M[k][j] read from LDS-staged raw tri (ds_read2, offsets in immediates).
// Staging: CH=8-step (1KB) chunks, one global_load_lds width=16 per task
// per chunk, NBUF=4 buffers, WAITVM(6) = constant distance-3 pipeline.
// Tail prefetches past a task's last chunk re-read the task's own chunk 0.
// Task-length mismatch within a wave: tail LDS slots overwritten with
// IDENTITY matrices so extra steps are no-ops (uniform compute, no masks).
// segout stores P^T so combine reads each segment matrix as one float4.
//
// amps_combine v9: 512 single-wave blocks (full-GPU spread), tiered segout
// loads (T in {4,8,16} compile-time — mean nseg ~8.5, avoids ~45% garbage
// fetch). v8's 4096 device-scope atomicAdds to ONE cache line (4x v7) are
// the suspected +5us regression — v9 removes atomics entirely: each block
// writes its 8-float partial to part[blockIdx], and a trivial 1-block
// amps_reduce kernel does the deterministic 512-way sum + first-pos term.

#define NPOS   1024
#define SEGLEN 64
#define MAXSEG 16
#define CH     8
#define NBUF   4
#define NWAVE  4344                    // 8688 tasks / 2 per wave
#define NCOMB  512                     // combine blocks (2 chains each)
#define TRI_ELEMS (523776 * 32)

template<int l>
__device__ __forceinline__ float qb(float x) {
    constexpr int ctrl = l * 0x55;     // quad_perm broadcast lane l
    return __int_as_float(__builtin_amdgcn_update_dpp(
        __float_as_int(x), __float_as_int(x), ctrl, 0xF, 0xF, false));
}
template<int ctrl>
__device__ __forceinline__ float qperm(float x) {
    return __int_as_float(__builtin_amdgcn_update_dpp(
        __float_as_int(x), __float_as_int(x), ctrl, 0xF, 0xF, false));
}

__device__ __forceinline__ void gl_lds16(const float* g, float* l) {
    __builtin_amdgcn_global_load_lds(
        (const __attribute__((address_space(1))) void*)g,
        (__attribute__((address_space(3))) void*)l, 16, 0, 0);
}

// wait until <=N vmem ops outstanding (N<=15); lgkm/exp ignored (gfx9 enc)
#define WAITVM(N) __builtin_amdgcn_s_waitcnt((N) | 0x0F70)

__device__ __forceinline__ void decode_task(int id, int& s, int& n) {
    int base = 0, cnt = 1023;
    s = 0;
    while (id >= base + cnt) { base += cnt; s++; cnt -= SEGLEN; }
    n = 1022 - (id - base);            // long chains first within each class
}

__global__ __launch_bounds__(64) void amps_seg(
        const float* __restrict__ data,   // (8, 1024)
        const float* __restrict__ tri,    // (523776, 4, 4, 2)
        float* __restrict__ segout)       // (1023, 16, 8, 4, 4) = P^T per seg
{
    const int lane = threadIdx.x;
    const int w    = blockIdx.x;          // wave id 0..4343
    const int t    = lane >> 5;           // task half 0/1
    const int q    = lane & 31;
    const int b    = q >> 2;              // batch
    const int i    = q & 3;               // row of C (also mask-quarter role)

    int sA, nA, sB, nB;
    decode_task(2 * w,     sA, nA);
    decode_task(2 * w + 1, sB, nB);
    const int g0A = sA * SEGLEN,            g0B = sB * SEGLEN;
    const int stepsA = min(SEGLEN, nA + 1 - g0A);
    const int stepsB = min(SEGLEN, nB + 1 - g0B);
    const int tstA = (nA * (nA + 1) / 2 + g0A) * 32;
    const int tstB = (nB * (nB + 1) / 2 + g0B) * 32;

    const int nchA = (stepsA >> 3) + ((stepsA & 7) ? 1 : 0);
    const int nchB = (stepsB >> 3) + ((stepsB & 7) ? 1 : 0);
    const int nch  = max(nchA, nchB);     // wave-uniform loop bound

    // my-task view (per lane; uniform per half-wave)
    const int g0_my    = t ? g0B : g0A;
    const int steps_my = t ? stepsB : stepsA;
    const int chunkf   = steps_my >> 3;
    const int rem      = steps_my & 7;
    const int n_my     = t ? nB : nA;
    const int s_my     = t ? sB : sA;

    __shared__ float lds[2][NBUF * CH * 32];   // 2 tasks x 1KB x 4 bufs

    // ---- per-lane 64-bit sel mask (bit=1 where data != 1.0) ----
    // half-lane q covers (batch q>>2, quarter q&3): 16 positions.
    unsigned m0, m1;
    {
        const float4* dp4 =
            (const float4*)(data + b * NPOS + g0_my + i * 16);
        float4 f[4];
        #pragma unroll
        for (int u = 0; u < 4; u++) f[u] = dp4[u];
        unsigned piece = 0;
        #pragma unroll
        for (int u = 0; u < 4; u++) {
            piece |= (f[u].x != 1.0f) ? (1u << (u * 4 + 0)) : 0u;
            piece |= (f[u].y != 1.0f) ? (1u << (u * 4 + 1)) : 0u;
            piece |= (f[u].z != 1.0f) ? (1u << (u * 4 + 2)) : 0u;
            piece |= (f[u].w != 1.0f) ? (1u << (u * 4 + 3)) : 0u;
        }
        m0 = (unsigned)__shfl((int)piece, t * 32 + b * 4 + 0)
           | ((unsigned)__shfl((int)piece, t * 32 + b * 4 + 1) << 16);
        m1 = (unsigned)__shfl((int)piece, t * 32 + b * 4 + 2)
           | ((unsigned)__shfl((int)piece, t * 32 + b * 4 + 3) << 16);
    }

    // stage chunk c of each task; chunks past the task's end re-read the
    // task's own chunk 0 (keeps vmem issue count -> WAITVM math intact,
    // turns over-fetch into L2 hits)
    auto stageA = [&](int c) {
        const int cc = (c < nchA) ? c : 0;
        int off = min(tstA + cc * 256 + lane * 4, TRI_ELEMS - 4);
        gl_lds16(tri + off, &lds[0][(c & (NBUF - 1)) * 256]);
    };
    auto stageB = [&](int c) {
        const int cc = (c < nchB) ? c : 0;
        int off = min(tstB + cc * 256 + lane * 4, TRI_ELEMS - 4);
        gl_lds16(tri + off, &lds[1][(c & (NBUF - 1)) * 256]);
    };

    stageA(0); stageB(0);
    stageA(1); stageB(1);
    stageA(2); stageB(2);

    float* __restrict__ mybuf = &lds[t][0];

    float c0 = (i == 0) ? 1.0f : 0.0f;    // row i of identity
    float c1 = (i == 1) ? 1.0f : 0.0f;
    float c2 = (i == 2) ? 1.0f : 0.0f;
    float c3 = (i == 3) ? 1.0f : 0.0f;

    const float idval = ((q >> 3) == ((q >> 1) & 3)) ? 1.0f : 0.0f;

    for (int c = 0; c < nch; c++) {
        stageA(c + 3); stageB(c + 3);
        WAITVM(6);                         // chunk c staged; c+1..c+3 in flight

        // identity-fill tail slots of my task's buffer (rare path)
        if (c >= chunkf) {
            const int mstart = (c == chunkf) ? rem : 0;
            float* bp = mybuf + (c & (NBUF - 1)) * 256 + q;
            for (int m = mstart; m < CH; m++) bp[m * 32] = idval;
        }

        const unsigned word = (c < 4) ? m0 : m1;
        const unsigned bits = (word >> ((c & 3) * 8)) & 0xFFu;
        const float* __restrict__ buf = mybuf + (c & (NBUF - 1)) * 256;

        #pragma unroll
        for (int m = 0; m < CH; m++) {
            const float* p = buf + m * 32 + ((bits >> m) & 1u);
            // M[k][j] at p[k*8 + j*2]; 4 independent FMA chains (j=0..3)
            float n0 = fmaf(c3, p[24], fmaf(c2, p[16], fmaf(c1, p[8],  c0 * p[0])));
            float n1 = fmaf(c3, p[26], fmaf(c2, p[18], fmaf(c1, p[10], c0 * p[2])));
            float n2 = fmaf(c3, p[28], fmaf(c2, p[20], fmaf(c1, p[12], c0 * p[4])));
            float n3 = fmaf(c3, p[30], fmaf(c2, p[22], fmaf(c1, p[14], c0 * p[6])));
            c0 = n0; c1 = n1; c2 = n2; c3 = n3;
        }
    }

    // store P^T: element [j][i] = P[i][j] = c_j  (combine reads row r as float4)
    const size_t o = (((size_t)n_my * MAXSEG + s_my) * 8 + b) * 16 + i;
    segout[o +  0] = c0;
    segout[o +  4] = c1;
    segout[o +  8] = c2;
    segout[o + 12] = c3;
}

// apply up to T segment matrices (T compile-time so P[] is register-resident)
template<int T>
__device__ __forceinline__ float chain_apply(
        const float* __restrict__ basep, int nseg, int r)
{
    float4 P[T];
    #pragma unroll
    for (int s2 = 0; s2 < T; s2++)
        P[s2] = *(const float4*)(basep + s2 * 128);

    float v = (r == 0) ? 1.0f : 0.0f;
    #pragma unroll
    for (int s2 = 0; s2 < T; s2++) {
        float acc = qb<0>(v) * P[s2].x;
        acc = fmaf(qb<1>(v), P[s2].y, acc);
        acc = fmaf(qb<2>(v), P[s2].z, acc);
        float vn = fmaf(qb<3>(v), P[s2].w, acc);
        v = (s2 < nseg) ? vn : v;     // garbage/poison segments discarded
    }
    return v;
}

__global__ __launch_bounds__(64) void amps_combine(
        const float* __restrict__ segout, // (1023, 16, 8, 16) P^T
        const float* __restrict__ diag,   // (1024, 4, 2)
        const float* __restrict__ data,   // (8, 1024)
        float* __restrict__ part)         // (512, 8) per-block partials
{
    const int lane = threadIdx.x;
    const int t    = lane >> 5;           // chain slot in block, 0/1
    const int sub  = lane & 31;
    const int b    = sub >> 2;
    const int r    = sub & 3;
    const int n    = blockIdx.x * 2 + t;  // 0..1023 (1023 invalid)

    float res = 0.0f;
    if (n < NPOS - 1) {
        const int nseg = (n >> 6) + 1;    // 1..16  (SEGLEN=64)
        const float* basep = segout + (size_t)n * (MAXSEG * 128)
                           + b * 16 + r * 4;

        // block-uniform tier (both chains in block share it; per-lane nseg
        // guard inside chain_apply handles the exact count)
        const int tiermax = ((blockIdx.x * 2 + 1) >> 6) + 1;
        float v;
        if (tiermax <= 4)       v = chain_apply<4>(basep, nseg, r);
        else if (tiermax <= 8)  v = chain_apply<8>(basep, nseg, r);
        else                    v = chain_apply<16>(basep, nseg, r);

        const int pos = n + 1;
        const float* dg = diag + pos * 8 + r * 2;
        float o0 = v * dg[0];
        float o1 = v * dg[1];
        o0 += qperm<0xB1>(o0); o0 += qperm<0x4E>(o0);   // quad sum over r
        o1 += qperm<0xB1>(o1); o1 += qperm<0x4E>(o1);
        float mx  = fmaxf(o0, o1);
        float lse = mx + __logf(__expf(o0 - mx) + __expf(o1 - mx));
        float dsel = data[b * NPOS + pos];
        res = ((dsel == 1.0f) ? o0 : o1) - lse;
    }
    // in-wave gather: lane b<8 collects res of (t=0,b) at lane 4b and
    // (t=1,b) at lane 32+4b (both are r==0 lanes)
    float v0 = __shfl(res, (lane & 7) * 4);
    float v1 = __shfl(res, 32 + (lane & 7) * 4);
    if (lane < 8) part[blockIdx.x * 8 + lane] = v0 + v1;
}

__global__ __launch_bounds__(64) void amps_reduce(
        const float* __restrict__ part,   // (512, 8)
        const float* __restrict__ diag,   // (1024, 4, 2)
        const float* __restrict__ data,   // (8, 1024)
        float* __restrict__ out)          // (8)
{
    const int tid = threadIdx.x;
    const int b   = tid & 7;
    const int g   = tid >> 3;             // 0..7
    float s = 0.0f;
    for (int j = g; j < NCOMB; j += 8)    // wave reads 256B contiguous/iter
        s += part[j * 8 + b];
    __shared__ float sh[64];
    sh[tid] = s;
    __syncthreads();
    if (tid < 8) {
        float tot = 0.0f;
        #pragma unroll
        for (int gg = 0; gg < 8; gg++) tot += sh[gg * 8 + tid];
        // first-position term (broadcast diag[0,0] over batches)
        float o0 = diag[0], o1 = diag[1];
        float mx  = fmaxf(o0, o1);
        float lse = mx + __logf(__expf(o0 - mx) + __expf(o1 - mx));
        float d0  = data[tid * NPOS];
        tot += ((d0 == 1.0f) ? o0 : o1) - lse;
        out[tid] = tot;
    }
}

extern "C" void kernel_launch(void* const* d_in, const int* in_sizes, int n_in,
                              void* d_out, int out_size, void* d_ws, size_t ws_size,
                              hipStream_t stream)
{
    const float* data = (const float*)d_in[0];   // (8, 1024)
    const float* tri  = (const float*)d_in[1];   // (523776, 4, 4, 2)
    const float* diag = (const float*)d_in[2];   // (1024, 4, 2)

    float* segout = (float*)d_ws;                       // 8,380,416 B
    float* part   = (float*)d_ws + 523776 * 4;          // + (512,8) f32
    float* out    = (float*)d_out;                      // 8 floats

    amps_seg<<<dim3(NWAVE), dim3(64), 0, stream>>>(data, tri, segout);
    amps_combine<<<dim3(NCOMB), dim3(64), 0, stream>>>(segout, diag, data, part);
    amps_reduce<<<dim3(1), dim3(64), 0, stream>>>(part, diag, data, out);
}

// Round 4
// 118.519 us; speedup vs baseline: 1.1183x; 1.1183x over previous
//
#include <hip/hip_runtime.h>

// AMPS chain kernel v10 — row-read + DPP-broadcast inner loop. gfx950.
//
// amps_seg: each 64-lane wave processes TWO (chain,segment) tasks (32 lanes
// each). Lane = (task t, batch b, row i) holds row i of the running 4x4
// product C in 4 VGPRs.
// v10 inner loop: seg was LDS-ISSUE-bound (64 ds_read2/chunk/wave, one LDS
// pipe per CU -> ~3-4 TB/s effective, ~20us), not HBM-bound (floor 10.6us).
// The selection bit is uniform per (t,b) quad, so lane i now reads only ITS
// OWN row M[i][0..3] (2 ds_read2_b32 at base+i*8+bit, offsets 0/2 and 4/6)
// — 4x fewer LDS instructions — and gets M[k][j] via quad_perm DPP
// broadcasts (VALU pipe, 4 SIMDs deep vs 1 LDS pipe):
//   C'[i][j] = sum_k C[i][k] * qb<k>(r_j),  r_j = M[lane_row][j].
// Per step: 2 LDS reads + 16 dpp + 16 fma. LDS/CU and VALU/SIMD both ~2.2k
// cyc per 17-wave epoch -> internal ceiling ~9.8 TB/s -> seg HBM-bound.
// Staging unchanged: CH=8-step (1KB) chunks, one global_load_lds width=16
// per task per chunk, NBUF=4, WAITVM(6) distance-3 pipeline; tail
// prefetches clamp to own chunk 0; tail LDS slots identity-filled.
// segout stores P^T so combine reads each segment matrix as one float4.
//
// amps_combine: reverted EXACTLY to the measured-best round-1 form
// (128 blocks x 256 threads, full P[16] loads, LDS + 1024 atomicAdds);
// the v8/v9 combine restructures regressed +5/+15us for unpredicted
// reasons — abandoned.

#define NPOS   1024
#define SEGLEN 64
#define MAXSEG 16
#define CH     8
#define NBUF   4
#define NWAVE  4344                    // 8688 tasks / 2 per wave
#define TRI_ELEMS (523776 * 32)

template<int l>
__device__ __forceinline__ float qb(float x) {
    constexpr int ctrl = l * 0x55;     // quad_perm broadcast lane l
    return __int_as_float(__builtin_amdgcn_update_dpp(
        __float_as_int(x), __float_as_int(x), ctrl, 0xF, 0xF, false));
}
template<int ctrl>
__device__ __forceinline__ float qperm(float x) {
    return __int_as_float(__builtin_amdgcn_update_dpp(
        __float_as_int(x), __float_as_int(x), ctrl, 0xF, 0xF, false));
}

__device__ __forceinline__ void gl_lds16(const float* g, float* l) {
    __builtin_amdgcn_global_load_lds(
        (const __attribute__((address_space(1))) void*)g,
        (__attribute__((address_space(3))) void*)l, 16, 0, 0);
}

// wait until <=N vmem ops outstanding (N<=15); lgkm/exp ignored (gfx9 enc)
#define WAITVM(N) __builtin_amdgcn_s_waitcnt((N) | 0x0F70)

__device__ __forceinline__ void decode_task(int id, int& s, int& n) {
    int base = 0, cnt = 1023;
    s = 0;
    while (id >= base + cnt) { base += cnt; s++; cnt -= SEGLEN; }
    n = 1022 - (id - base);            // long chains first within each class
}

__global__ __launch_bounds__(64) void amps_seg(
        const float* __restrict__ data,   // (8, 1024)
        const float* __restrict__ tri,    // (523776, 4, 4, 2)
        float* __restrict__ segout,       // (1023, 16, 8, 4, 4) = P^T per seg
        float* __restrict__ out)          // (8) — zeroed here by block 0
{
    const int lane = threadIdx.x;
    const int w    = blockIdx.x;          // wave id 0..4343
    const int t    = lane >> 5;           // task half 0/1
    const int q    = lane & 31;
    const int b    = q >> 2;              // batch
    const int i    = q & 3;               // row of C (also mask-quarter role)

    if (w == 0 && lane < 8) out[lane] = 0.0f;   // replaces hipMemsetAsync

    int sA, nA, sB, nB;
    decode_task(2 * w,     sA, nA);
    decode_task(2 * w + 1, sB, nB);
    const int g0A = sA * SEGLEN,            g0B = sB * SEGLEN;
    const int stepsA = min(SEGLEN, nA + 1 - g0A);
    const int stepsB = min(SEGLEN, nB + 1 - g0B);
    const int tstA = (nA * (nA + 1) / 2 + g0A) * 32;
    const int tstB = (nB * (nB + 1) / 2 + g0B) * 32;

    const int nchA = (stepsA >> 3) + ((stepsA & 7) ? 1 : 0);
    const int nchB = (stepsB >> 3) + ((stepsB & 7) ? 1 : 0);
    const int nch  = max(nchA, nchB);     // wave-uniform loop bound

    // my-task view (per lane; uniform per half-wave)
    const int g0_my    = t ? g0B : g0A;
    const int steps_my = t ? stepsB : stepsA;
    const int chunkf   = steps_my >> 3;
    const int rem      = steps_my & 7;
    const int n_my     = t ? nB : nA;
    const int s_my     = t ? sB : sA;

    __shared__ float lds[2][NBUF * CH * 32];   // 2 tasks x 1KB x 4 bufs

    // ---- per-lane 64-bit sel mask (bit=1 where data != 1.0) ----
    // half-lane q covers (batch q>>2, quarter q&3): 16 positions.
    unsigned m0, m1;
    {
        const float4* dp4 =
            (const float4*)(data + b * NPOS + g0_my + i * 16);
        float4 f[4];
        #pragma unroll
        for (int u = 0; u < 4; u++) f[u] = dp4[u];
        unsigned piece = 0;
        #pragma unroll
        for (int u = 0; u < 4; u++) {
            piece |= (f[u].x != 1.0f) ? (1u << (u * 4 + 0)) : 0u;
            piece |= (f[u].y != 1.0f) ? (1u << (u * 4 + 1)) : 0u;
            piece |= (f[u].z != 1.0f) ? (1u << (u * 4 + 2)) : 0u;
            piece |= (f[u].w != 1.0f) ? (1u << (u * 4 + 3)) : 0u;
        }
        m0 = (unsigned)__shfl((int)piece, t * 32 + b * 4 + 0)
           | ((unsigned)__shfl((int)piece, t * 32 + b * 4 + 1) << 16);
        m1 = (unsigned)__shfl((int)piece, t * 32 + b * 4 + 2)
           | ((unsigned)__shfl((int)piece, t * 32 + b * 4 + 3) << 16);
    }

    // stage chunk c of each task; chunks past the task's end re-read the
    // task's own chunk 0 (keeps vmem issue count -> WAITVM math intact,
    // turns over-fetch into L2 hits)
    auto stageA = [&](int c) {
        const int cc = (c < nchA) ? c : 0;
        int off = min(tstA + cc * 256 + lane * 4, TRI_ELEMS - 4);
        gl_lds16(tri + off, &lds[0][(c & (NBUF - 1)) * 256]);
    };
    auto stageB = [&](int c) {
        const int cc = (c < nchB) ? c : 0;
        int off = min(tstB + cc * 256 + lane * 4, TRI_ELEMS - 4);
        gl_lds16(tri + off, &lds[1][(c & (NBUF - 1)) * 256]);
    };

    stageA(0); stageB(0);
    stageA(1); stageB(1);
    stageA(2); stageB(2);

    float* __restrict__ mybuf = &lds[t][0];

    float c0 = (i == 0) ? 1.0f : 0.0f;    // row i of identity
    float c1 = (i == 1) ? 1.0f : 0.0f;
    float c2 = (i == 2) ? 1.0f : 0.0f;
    float c3 = (i == 3) ? 1.0f : 0.0f;

    const float idval = ((q >> 3) == ((q >> 1) & 3)) ? 1.0f : 0.0f;

    for (int c = 0; c < nch; c++) {
        stageA(c + 3); stageB(c + 3);
        WAITVM(6);                         // chunk c staged; c+1..c+3 in flight

        // identity-fill tail slots of my task's buffer (rare path)
        if (c >= chunkf) {
            const int mstart = (c == chunkf) ? rem : 0;
            float* bp = mybuf + (c & (NBUF - 1)) * 256 + q;
            for (int m = mstart; m < CH; m++) bp[m * 32] = idval;
        }

        const unsigned word = (c < 4) ? m0 : m1;
        const unsigned bits = (word >> ((c & 3) * 8)) & 0xFFu;
        const float* __restrict__ buf = mybuf + (c & (NBUF - 1)) * 256;

        #pragma unroll
        for (int m = 0; m < CH; m++) {
            // lane i reads ONLY row i of M (bit uniform per quad):
            // r_j = M[i][j] at base + i*8 + j*2 + bit  -> 2x ds_read2_b32
            const float* pr = buf + m * 32 + i * 8 + ((bits >> m) & 1u);
            const float r0 = pr[0];
            const float r1 = pr[2];
            const float r2 = pr[4];
            const float r3 = pr[6];
            // C'[i][j] = sum_k C[i][k] * M[k][j]; M[k][j] = qb<k>(r_j)
            float n0 = fmaf(c3, qb<3>(r0), fmaf(c2, qb<2>(r0),
                       fmaf(c1, qb<1>(r0), c0 * qb<0>(r0))));
            float n1 = fmaf(c3, qb<3>(r1), fmaf(c2, qb<2>(r1),
                       fmaf(c1, qb<1>(r1), c0 * qb<0>(r1))));
            float n2 = fmaf(c3, qb<3>(r2), fmaf(c2, qb<2>(r2),
                       fmaf(c1, qb<1>(r2), c0 * qb<0>(r2))));
            float n3 = fmaf(c3, qb<3>(r3), fmaf(c2, qb<2>(r3),
                       fmaf(c1, qb<1>(r3), c0 * qb<0>(r3))));
            c0 = n0; c1 = n1; c2 = n2; c3 = n3;
        }
    }

    // store P^T: element [j][i] = P[i][j] = c_j  (combine reads row r as float4)
    const size_t o = (((size_t)n_my * MAXSEG + s_my) * 8 + b) * 16 + i;
    segout[o +  0] = c0;
    segout[o +  4] = c1;
    segout[o +  8] = c2;
    segout[o + 12] = c3;
}

__global__ __launch_bounds__(256) void amps_combine(
        const float* __restrict__ segout, // (1023, 16, 8, 16) P^T
        const float* __restrict__ diag,   // (1024, 4, 2)
        const float* __restrict__ data,   // (8, 1024)
        float* __restrict__ out)          // (8) — zeroed by amps_seg
{
    const int tid = threadIdx.x;
    const int q   = tid >> 5;             // chain slot in block, 0..7
    const int sub = tid & 31;
    const int b   = sub >> 2;
    const int r   = sub & 3;
    const int n   = blockIdx.x * 8 + q;   // 0..1023 (1023 invalid)

    __shared__ float sh[64];

    float res = 0.0f;
    if (n < NPOS - 1) {
        const int nseg = n / SEGLEN + 1;  // 1..16
        // prefetch all 16 segment columns (float4 each; unused slots garbage)
        const float* basep = segout + (size_t)n * (MAXSEG * 128)
                           + b * 16 + r * 4;
        float4 P[MAXSEG];
        #pragma unroll
        for (int s2 = 0; s2 < MAXSEG; s2++)
            P[s2] = *(const float4*)(basep + s2 * 128);

        float v = (r == 0) ? 1.0f : 0.0f;
        #pragma unroll
        for (int s2 = 0; s2 < MAXSEG; s2++) {
            float acc = qb<0>(v) * P[s2].x;
            acc = fmaf(qb<1>(v), P[s2].y, acc);
            acc = fmaf(qb<2>(v), P[s2].z, acc);
            float vn = fmaf(qb<3>(v), P[s2].w, acc);
            v = (s2 < nseg) ? vn : v;     // garbage segments discarded
        }

        const int pos = n + 1;
        const float* dg = diag + pos * 8 + r * 2;
        float o0 = v * dg[0];
        float o1 = v * dg[1];
        o0 += qperm<0xB1>(o0); o0 += qperm<0x4E>(o0);   // quad sum over r
        o1 += qperm<0xB1>(o1); o1 += qperm<0x4E>(o1);
        float mx  = fmaxf(o0, o1);
        float lse = mx + __logf(__expf(o0 - mx) + __expf(o1 - mx));
        float dsel = data[b * NPOS + pos];
        res = ((dsel == 1.0f) ? o0 : o1) - lse;
    }
    if (r == 0) sh[q * 8 + b] = res;
    __syncthreads();
    if (tid < 8) {
        float ssum = 0.0f;
        #pragma unroll
        for (int qq = 0; qq < 8; qq++) ssum += sh[qq * 8 + tid];
        if (blockIdx.x == 0) {
            float o0 = diag[0], o1 = diag[1];
            float mx  = fmaxf(o0, o1);
            float lse = mx + __logf(__expf(o0 - mx) + __expf(o1 - mx));
            float d0  = data[tid * NPOS];
            ssum += ((d0 == 1.0f) ? o0 : o1) - lse;
        }
        atomicAdd(out + tid, ssum);
    }
}

extern "C" void kernel_launch(void* const* d_in, const int* in_sizes, int n_in,
                              void* d_out, int out_size, void* d_ws, size_t ws_size,
                              hipStream_t stream)
{
    const float* data = (const float*)d_in[0];   // (8, 1024)
    const float* tri  = (const float*)d_in[1];   // (523776, 4, 4, 2)
    const float* diag = (const float*)d_in[2];   // (1024, 4, 2)

    float* segout = (float*)d_ws;                // 1023*16*8*16*4 = 8,380,416 B
    float* out    = (float*)d_out;               // 8 floats

    amps_seg<<<dim3(NWAVE), dim3(64), 0, stream>>>(data, tri, segout, out);
    amps_combine<<<dim3(128), dim3(256), 0, stream>>>(segout, diag, data, out);
}

// Round 5
// 111.430 us; speedup vs baseline: 1.1894x; 1.0636x over previous
//
#include <hip/hip_runtime.h>

// AMPS chain kernel v11 == v7 verbatim (measured best: 112.0us, round 1).
// Restored after v8 (combine restructure, +5us), v9 (3-kernel reduce,
// +15us), v10 (DPP inner loop, +5us) all regressed vs prediction.
//
// amps_seg: each 64-lane wave processes TWO (chain,segment) tasks (32 lanes
// each). Lane = (task t, batch b, row i) holds row i of the running 4x4
// product C in 4 VGPRs. Step update C[i][j] = sum_k C[i][k]*M[k][j] = 16
// register FMAs (4 independent chains of 4) — no DPP, no cross-lane deps.
// M[k][j] read from LDS-staged raw tri (ds_read2, offsets in immediates).
// Staging: CH=8-step (1KB) chunks, one global_load_lds width=16 per task
// per chunk, NBUF=4 buffers, WAITVM(6) = constant distance-3 pipeline.
// SEGLEN=64: 8688 tasks / 4344 waves (~17 blocks/CU TLP).
// Tail prefetches past a task's last chunk re-read the task's own chunk 0
// (same vmem issue count -> WAITVM distances intact, over-fetch = L2 hits).
// Task-length mismatch within a wave: tail LDS slots overwritten with
// IDENTITY matrices so extra steps are no-ops (uniform compute, no masks).
// segout stores P^T so combine reads each segment matrix as one float4.
//
// Measured pipe model (per CU): seg inner loop = 8 ds_read2_b32/step
// ~52 LDS-pipe cyc x ~1035 wave-steps ~= 22us (LDS-bound); VALU ~4us;
// HBM floor 10.6us. DPP-sharing (v10) and deinterleave re-stage paths to
// convert LDS->HBM-bound both measured as losses; ~83us of the timed
// region is harness poison fills (uncontrollable).

#define NPOS   1024
#define SEGLEN 64
#define MAXSEG 16
#define CH     8
#define NBUF   4
#define NWAVE  4344                    // 8688 tasks / 2 per wave
#define TRI_ELEMS (523776 * 32)

template<int l>
__device__ __forceinline__ float qb(float x) {
    constexpr int ctrl = l * 0x55;     // quad_perm broadcast lane l
    return __int_as_float(__builtin_amdgcn_update_dpp(
        __float_as_int(x), __float_as_int(x), ctrl, 0xF, 0xF, false));
}
template<int ctrl>
__device__ __forceinline__ float qperm(float x) {
    return __int_as_float(__builtin_amdgcn_update_dpp(
        __float_as_int(x), __float_as_int(x), ctrl, 0xF, 0xF, false));
}

__device__ __forceinline__ void gl_lds16(const float* g, float* l) {
    __builtin_amdgcn_global_load_lds(
        (const __attribute__((address_space(1))) void*)g,
        (__attribute__((address_space(3))) void*)l, 16, 0, 0);
}

// wait until <=N vmem ops outstanding (N<=15); lgkm/exp ignored (gfx9 enc)
#define WAITVM(N) __builtin_amdgcn_s_waitcnt((N) | 0x0F70)

__device__ __forceinline__ void decode_task(int id, int& s, int& n) {
    int base = 0, cnt = 1023;
    s = 0;
    while (id >= base + cnt) { base += cnt; s++; cnt -= SEGLEN; }
    n = 1022 - (id - base);            // long chains first within each class
}

__global__ __launch_bounds__(64) void amps_seg(
        const float* __restrict__ data,   // (8, 1024)
        const float* __restrict__ tri,    // (523776, 4, 4, 2)
        float* __restrict__ segout,       // (1023, 16, 8, 4, 4) = P^T per seg
        float* __restrict__ out)          // (8) — zeroed here by block 0
{
    const int lane = threadIdx.x;
    const int w    = blockIdx.x;          // wave id 0..4343
    const int t    = lane >> 5;           // task half 0/1
    const int q    = lane & 31;
    const int b    = q >> 2;              // batch
    const int i    = q & 3;               // row of C (also mask-quarter role)

    if (w == 0 && lane < 8) out[lane] = 0.0f;   // replaces hipMemsetAsync

    int sA, nA, sB, nB;
    decode_task(2 * w,     sA, nA);
    decode_task(2 * w + 1, sB, nB);
    const int g0A = sA * SEGLEN,            g0B = sB * SEGLEN;
    const int stepsA = min(SEGLEN, nA + 1 - g0A);
    const int stepsB = min(SEGLEN, nB + 1 - g0B);
    const int tstA = (nA * (nA + 1) / 2 + g0A) * 32;
    const int tstB = (nB * (nB + 1) / 2 + g0B) * 32;

    const int nchA = (stepsA >> 3) + ((stepsA & 7) ? 1 : 0);
    const int nchB = (stepsB >> 3) + ((stepsB & 7) ? 1 : 0);
    const int nch  = max(nchA, nchB);     // wave-uniform loop bound

    // my-task view (per lane; uniform per half-wave)
    const int g0_my    = t ? g0B : g0A;
    const int steps_my = t ? stepsB : stepsA;
    const int chunkf   = steps_my >> 3;
    const int rem      = steps_my & 7;
    const int n_my     = t ? nB : nA;
    const int s_my     = t ? sB : sA;

    __shared__ float lds[2][NBUF * CH * 32];   // 2 tasks x 1KB x 4 bufs

    // ---- per-lane 64-bit sel mask (bit=1 where data != 1.0) ----
    // half-lane q covers (batch q>>2, quarter q&3): 16 positions.
    unsigned m0, m1;
    {
        const float4* dp4 =
            (const float4*)(data + b * NPOS + g0_my + i * 16);
        float4 f[4];
        #pragma unroll
        for (int u = 0; u < 4; u++) f[u] = dp4[u];
        unsigned piece = 0;
        #pragma unroll
        for (int u = 0; u < 4; u++) {
            piece |= (f[u].x != 1.0f) ? (1u << (u * 4 + 0)) : 0u;
            piece |= (f[u].y != 1.0f) ? (1u << (u * 4 + 1)) : 0u;
            piece |= (f[u].z != 1.0f) ? (1u << (u * 4 + 2)) : 0u;
            piece |= (f[u].w != 1.0f) ? (1u << (u * 4 + 3)) : 0u;
        }
        m0 = (unsigned)__shfl((int)piece, t * 32 + b * 4 + 0)
           | ((unsigned)__shfl((int)piece, t * 32 + b * 4 + 1) << 16);
        m1 = (unsigned)__shfl((int)piece, t * 32 + b * 4 + 2)
           | ((unsigned)__shfl((int)piece, t * 32 + b * 4 + 3) << 16);
    }

    // stage chunk c of each task; chunks past the task's end re-read the
    // task's own chunk 0 (keeps vmem issue count -> WAITVM math intact,
    // turns over-fetch into L2 hits)
    auto stageA = [&](int c) {
        const int cc = (c < nchA) ? c : 0;
        int off = min(tstA + cc * 256 + lane * 4, TRI_ELEMS - 4);
        gl_lds16(tri + off, &lds[0][(c & (NBUF - 1)) * 256]);
    };
    auto stageB = [&](int c) {
        const int cc = (c < nchB) ? c : 0;
        int off = min(tstB + cc * 256 + lane * 4, TRI_ELEMS - 4);
        gl_lds16(tri + off, &lds[1][(c & (NBUF - 1)) * 256]);
    };

    stageA(0); stageB(0);
    stageA(1); stageB(1);
    stageA(2); stageB(2);

    float* __restrict__ mybuf = &lds[t][0];

    float c0 = (i == 0) ? 1.0f : 0.0f;    // row i of identity
    float c1 = (i == 1) ? 1.0f : 0.0f;
    float c2 = (i == 2) ? 1.0f : 0.0f;
    float c3 = (i == 3) ? 1.0f : 0.0f;

    const float idval = ((q >> 3) == ((q >> 1) & 3)) ? 1.0f : 0.0f;

    for (int c = 0; c < nch; c++) {
        stageA(c + 3); stageB(c + 3);
        WAITVM(6);                         // chunk c staged; c+1..c+3 in flight

        // identity-fill tail slots of my task's buffer (rare path)
        if (c >= chunkf) {
            const int mstart = (c == chunkf) ? rem : 0;
            float* bp = mybuf + (c & (NBUF - 1)) * 256 + q;
            for (int m = mstart; m < CH; m++) bp[m * 32] = idval;
        }

        const unsigned word = (c < 4) ? m0 : m1;
        const unsigned bits = (word >> ((c & 3) * 8)) & 0xFFu;
        const float* __restrict__ buf = mybuf + (c & (NBUF - 1)) * 256;

        #pragma unroll
        for (int m = 0; m < CH; m++) {
            const float* p = buf + m * 32 + ((bits >> m) & 1u);
            // M[k][j] at p[k*8 + j*2]; 4 independent FMA chains (j=0..3)
            float n0 = fmaf(c3, p[24], fmaf(c2, p[16], fmaf(c1, p[8],  c0 * p[0])));
            float n1 = fmaf(c3, p[26], fmaf(c2, p[18], fmaf(c1, p[10], c0 * p[2])));
            float n2 = fmaf(c3, p[28], fmaf(c2, p[20], fmaf(c1, p[12], c0 * p[4])));
            float n3 = fmaf(c3, p[30], fmaf(c2, p[22], fmaf(c1, p[14], c0 * p[6])));
            c0 = n0; c1 = n1; c2 = n2; c3 = n3;
        }
    }

    // store P^T: element [j][i] = P[i][j] = c_j  (combine reads row r as float4)
    const size_t o = (((size_t)n_my * MAXSEG + s_my) * 8 + b) * 16 + i;
    segout[o +  0] = c0;
    segout[o +  4] = c1;
    segout[o +  8] = c2;
    segout[o + 12] = c3;
}

__global__ __launch_bounds__(256) void amps_combine(
        const float* __restrict__ segout, // (1023, 16, 8, 16) P^T
        const float* __restrict__ diag,   // (1024, 4, 2)
        const float* __restrict__ data,   // (8, 1024)
        float* __restrict__ out)          // (8) — zeroed by amps_seg
{
    const int tid = threadIdx.x;
    const int q   = tid >> 5;             // chain slot in block, 0..7
    const int sub = tid & 31;
    const int b   = sub >> 2;
    const int r   = sub & 3;
    const int n   = blockIdx.x * 8 + q;   // 0..1023 (1023 invalid)

    __shared__ float sh[64];

    float res = 0.0f;
    if (n < NPOS - 1) {
        const int nseg = n / SEGLEN + 1;  // 1..16
        // prefetch all 16 segment columns (float4 each; unused slots garbage)
        const float* basep = segout + (size_t)n * (MAXSEG * 128)
                           + b * 16 + r * 4;
        float4 P[MAXSEG];
        #pragma unroll
        for (int s2 = 0; s2 < MAXSEG; s2++)
            P[s2] = *(const float4*)(basep + s2 * 128);

        float v = (r == 0) ? 1.0f : 0.0f;
        #pragma unroll
        for (int s2 = 0; s2 < MAXSEG; s2++) {
            float acc = qb<0>(v) * P[s2].x;
            acc = fmaf(qb<1>(v), P[s2].y, acc);
            acc = fmaf(qb<2>(v), P[s2].z, acc);
            float vn = fmaf(qb<3>(v), P[s2].w, acc);
            v = (s2 < nseg) ? vn : v;     // garbage segments discarded
        }

        const int pos = n + 1;
        const float* dg = diag + pos * 8 + r * 2;
        float o0 = v * dg[0];
        float o1 = v * dg[1];
        o0 += qperm<0xB1>(o0); o0 += qperm<0x4E>(o0);   // quad sum over r
        o1 += qperm<0xB1>(o1); o1 += qperm<0x4E>(o1);
        float mx  = fmaxf(o0, o1);
        float lse = mx + __logf(__expf(o0 - mx) + __expf(o1 - mx));
        float dsel = data[b * NPOS + pos];
        res = ((dsel == 1.0f) ? o0 : o1) - lse;
    }
    if (r == 0) sh[q * 8 + b] = res;
    __syncthreads();
    if (tid < 8) {
        float ssum = 0.0f;
        #pragma unroll
        for (int qq = 0; qq < 8; qq++) ssum += sh[qq * 8 + tid];
        if (blockIdx.x == 0) {
            float o0 = diag[0], o1 = diag[1];
            float mx  = fmaxf(o0, o1);
            float lse = mx + __logf(__expf(o0 - mx) + __expf(o1 - mx));
            float d0  = data[tid * NPOS];
            ssum += ((d0 == 1.0f) ? o0 : o1) - lse;
        }
        atomicAdd(out + tid, ssum);
    }
}

extern "C" void kernel_launch(void* const* d_in, const int* in_sizes, int n_in,
                              void* d_out, int out_size, void* d_ws, size_t ws_size,
                              hipStream_t stream)
{
    const float* data = (const float*)d_in[0];   // (8, 1024)
    const float* tri  = (const float*)d_in[1];   // (523776, 4, 4, 2)
    const float* diag = (const float*)d_in[2];   // (1024, 4, 2)

    float* segout = (float*)d_ws;                // 1023*16*8*16*4 = 8,380,416 B
    float* out    = (float*)d_out;               // 8 floats

    amps_seg<<<dim3(NWAVE), dim3(64), 0, stream>>>(data, tri, segout, out);
    amps_combine<<<dim3(128), dim3(256), 0, stream>>>(segout, diag, data, out);
}